// Round 7
// baseline (961.553 us; speedup 1.0000x reference)
//
#include <hip/hip_runtime.h>
#include <stdint.h>

typedef unsigned long long u64;
typedef unsigned u32;

#define K 27
#define S 258
#define ENCMAX (4 * S * S * S)        // 68,694,048 possible keys

// ---------- pass 1: mark presence bits (one u64 atomicOr per z-run) ----------
__global__ void k_mark(const int* __restrict__ si, int N, u64* __restrict__ bits) {
    int idx = blockIdx.x * blockDim.x + threadIdx.x;
    if (idx >= N * 9) return;
    int n = idx / 9, run = idx - n * 9;
    int ox = run / 3, oy = run - ox * 3;
    int b = si[n], x = si[N + n], y = si[2 * N + n], z = si[3 * N + n];
    unsigned enc0 = (unsigned)(((b * S + x + ox) * S + (y + oy)) * S + z);
    unsigned w = enc0 >> 6; int bit = enc0 & 63;
    atomicOr(&bits[w], 7ull << bit);
    if (bit > 61) atomicOr(&bits[w + 1], 7ull >> (64 - bit));
}

// ---------- s1: tile popcounts + minE init + last-block scan of tsums --------
__global__ void s1_tilesum(const u64* __restrict__ bits, int* __restrict__ tsums,
                           int* __restrict__ minE, int NK, int NT,
                           u32* __restrict__ cnt) {
    __shared__ int s[512];
    __shared__ int lastf;
    int tid = threadIdx.x;
    const u64* p = bits + (size_t)blockIdx.x * 4096;
    int sum = 0;
    for (int j = tid; j < 4096; j += 512) sum += __popcll(p[j]);
    s[tid] = sum; __syncthreads();
    for (int off = 256; off > 0; off >>= 1) {
        if (tid < off) s[tid] += s[tid + off];
        __syncthreads();
    }
    if (tid == 0) tsums[blockIdx.x] = s[0];
    // fold: minE init
    for (int i = blockIdx.x * 512 + tid; i < NK; i += NT * 512)
        minE[i] = 0x7FFFFFFF;
    // last-block: exclusive scan of tsums (NT <= 512)
    __threadfence();
    if (tid == 0) { u32 t = atomicAdd(cnt, 1u); lastf = (t == (u32)(NT - 1)); }
    __syncthreads();
    if (!lastf) return;
    __threadfence();
    int v = (tid < NT) ? tsums[tid] : 0;
    s[tid] = v; __syncthreads();
    for (int off = 1; off < 512; off <<= 1) {
        int t = (tid >= off) ? s[tid - off] : 0;
        __syncthreads();
        s[tid] += t;
        __syncthreads();
    }
    if (tid < NT) tsums[tid] = s[tid] - v;
    if (tid == 511) tsums[NT] = s[511];
}

// ---------- s3: per-word exclusive popcount prefix ----------
__global__ void s3_wprefix(const u64* __restrict__ bits, const int* __restrict__ tsums,
                           u32* __restrict__ wprefix) {
    __shared__ int s[256];
    int tid = threadIdx.x;
    size_t base = (size_t)blockIdx.x * 4096 + (size_t)tid * 16;
    int pc[16]; int tsum = 0;
#pragma unroll
    for (int j = 0; j < 16; j++) { pc[j] = __popcll(bits[base + j]); tsum += pc[j]; }
    s[tid] = tsum; __syncthreads();
    for (int off = 1; off < 256; off <<= 1) {
        int t = (tid >= off) ? s[tid - off] : 0;
        __syncthreads();
        s[tid] += t;
        __syncthreads();
    }
    int run = tsums[blockIdx.x] + s[tid] - tsum;
#pragma unroll
    for (int j = 0; j < 16; j++) { wprefix[base + j] = (u32)run; run += pc[j]; }
}

// ---------- pass 2: dense key id per entry + min-e per key (L2-hot atomics) ---
__global__ void k_kid(const int* __restrict__ si, int N,
                      const u64* __restrict__ bits, const u32* __restrict__ wprefix,
                      int* __restrict__ kid, int* __restrict__ minE) {
    int idx = blockIdx.x * blockDim.x + threadIdx.x;
    if (idx >= N * 9) return;
    int n = idx / 9, run = idx - n * 9;
    int ox = run / 3, oy = run - ox * 3;
    int b = si[n], x = si[N + n], y = si[2 * N + n], z = si[3 * N + n];
    unsigned enc0 = (unsigned)(((b * S + x + ox) * S + (y + oy)) * S + z);
    int e0 = n * K + run * 3;
#pragma unroll
    for (int oz = 0; oz < 3; ++oz) {
        unsigned enc = enc0 + oz;
        unsigned w = enc >> 6; int bit = enc & 63;
        int kd = (int)wprefix[w] + __popcll(bits[w] & ((1ull << bit) - 1));
        kid[e0 + oz] = kd;
        atomicMin(&minE[kd], e0 + oz);
    }
}

// ---------- pass 3: tile first-counts + multi-bitmap + last-block bsums scan --
__global__ void k_flagsum(const int* __restrict__ kid, const int* __restrict__ minE,
                          int NK, int NB, u32* __restrict__ multibk,
                          int* __restrict__ bsums, u32* __restrict__ cnt) {
    __shared__ int s[1024];
    __shared__ int lastf;
    int tid = threadIdx.x;
    int base = blockIdx.x * 4096 + tid * 4;
    int4 kv = *(const int4*)(kid + base);
    int kvv[4] = {kv.x, kv.y, kv.z, kv.w};
    int sum = 0;
#pragma unroll
    for (int j = 0; j < 4; j++) {
        int e = base + j;
        if (e < NK) {
            int kd = kvv[j];
            if (minE[kd] == e) sum += 1;
            else atomicOr(&multibk[kd >> 5], 1u << (kd & 31));
        }
    }
    s[tid] = sum; __syncthreads();
    for (int off = 512; off > 0; off >>= 1) {
        if (tid < off) s[tid] += s[tid + off];
        __syncthreads();
    }
    if (tid == 0) bsums[blockIdx.x] = s[0];
    __threadfence();
    if (tid == 0) { u32 t = atomicAdd(cnt, 1u); lastf = (t == (u32)(NB - 1)); }
    __syncthreads();
    if (!lastf) return;
    __threadfence();
    int v = (tid < NB) ? bsums[tid] : 0;
    s[tid] = v; __syncthreads();
    for (int off = 1; off < 1024; off <<= 1) {
        int t = (tid >= off) ? s[tid - off] : 0;
        __syncthreads();
        s[tid] += t;
        __syncthreads();
    }
    if (tid < NB) bsums[tid] = s[tid] - v;
    if (tid == 1023) bsums[NB] = s[1023];
}

// ---------- scan C: ranks, out_key, rank_key, multi-row zero, tail ----------
__global__ void k_scanC(const int* __restrict__ kid, const int* __restrict__ minE,
                        const int* __restrict__ bsums, const int* __restrict__ si,
                        const u32* __restrict__ multibk, int N, int NK, int NB,
                        float* __restrict__ out_key, int* __restrict__ rank_key,
                        float4* __restrict__ outF4) {
    __shared__ int s[256];
    int tid = threadIdx.x;
    int base = blockIdx.x * 4096 + tid * 16;
    int kv[16];
    *(int4*)(kv + 0)  = *(const int4*)(kid + base + 0);
    *(int4*)(kv + 4)  = *(const int4*)(kid + base + 4);
    *(int4*)(kv + 8)  = *(const int4*)(kid + base + 8);
    *(int4*)(kv + 12) = *(const int4*)(kid + base + 12);
    int f[16]; int tsum = 0;
#pragma unroll
    for (int j = 0; j < 16; j++) {
        int e = base + j;
        f[j] = (e < NK && minE[kv[j]] == e) ? 1 : 0;
        tsum += f[j];
    }
    s[tid] = tsum; __syncthreads();
    for (int off = 1; off < 256; off <<= 1) {
        int t = (tid >= off) ? s[tid - off] : 0;
        __syncthreads();
        s[tid] += t;
        __syncthreads();
    }
    int offset = bsums[blockIdx.x] + s[tid] - tsum;
    float4 zf = {0.f, 0.f, 0.f, 0.f};
    int run = 0;
#pragma unroll
    for (int j = 0; j < 16; j++) {
        int e = base + j;
        if (f[j]) {
            int rank = offset + run;
            int n = e / K; int m = e - n * K;
            int x = si[N + n], y = si[2 * N + n], z = si[3 * N + n];
            int ox = m / 9; int rm = m - ox * 9; int oy = rm / 3; int oz = rm - oy * 3;
            out_key[(size_t)rank * 3 + 0] = (float)(x + ox - 1);
            out_key[(size_t)rank * 3 + 1] = (float)(y + oy - 1);
            out_key[(size_t)rank * 3 + 2] = (float)(z + oz - 1);
            int kd = kv[j];
            rank_key[kd] = rank;
            if ((multibk[kd >> 5] >> (kd & 31)) & 1) {
                float4* q = outF4 + (size_t)rank * 8;
#pragma unroll
                for (int q8 = 0; q8 < 8; q8++) q[q8] = zf;
            }
        }
        run += f[j];
    }
    int U = bsums[NB];
    int rows = NK - U;
    int gs = gridDim.x * blockDim.x;
    for (int i = blockIdx.x * blockDim.x + tid; i < rows; i += gs) {
        int row = U + i;
        float4* q = outF4 + (size_t)row * 8;
#pragma unroll
        for (int q8 = 0; q8 < 8; q8++) q[q8] = zf;
        out_key[(size_t)row * 3 + 0] = -1.0f;
        out_key[(size_t)row * 3 + 1] = -1.0f;
        out_key[(size_t)row * 3 + 2] = -1.0f;
    }
}

// ---------- final: kernel_map + coalesced feature scatter (8 lanes/row) ------
__global__ void k_final(const int* __restrict__ kid, const int* __restrict__ rank_key,
                        const u32* __restrict__ multibk,
                        const float4* __restrict__ feat4,
                        float* __restrict__ km, float* __restrict__ outF, int NK) {
    int idx = blockIdx.x * blockDim.x + threadIdx.x;
    if (idx >= NK * 8) return;
    int e = idx >> 3, g = idx & 7;
    int kd = kid[e];
    int uid = rank_key[kd];
    int multi = (multibk[kd >> 5] >> (kd & 31)) & 1;
    int n = e / K, m = e - n * K;
    float4 v = feat4[(size_t)n * 8 + g];
    float* dst = outF + (size_t)uid * 32 + g * 4;
    if (multi) {
        atomicAdd(dst + 0, v.x);
        atomicAdd(dst + 1, v.y);
        atomicAdd(dst + 2, v.z);
        atomicAdd(dst + 3, v.w);
    } else {
        *(float4*)dst = v;
    }
    if (g < 3)
        km[(size_t)e * 3 + g] = (g == 0) ? (float)n
                               : ((g == 1) ? (float)uid : (float)m);
}

extern "C" void kernel_launch(void* const* d_in, const int* in_sizes, int n_in,
                              void* d_out, int out_size, void* d_ws, size_t ws_size,
                              hipStream_t stream) {
    const int* si = (const int*)d_in[0];
    const float4* feat4 = (const float4*)d_in[1];
    int N = in_sizes[0] / 4;
    int NK = N * K;                            // 2,700,000
    int NKp = (NK + 4095) & ~4095;
    int NB = NKp / 4096;                       // ~660 (<=1024)
    int nkw = (NK + 31) / 32;

    int NW = (ENCMAX + 63) / 64;               // 1,073,345 bitmap words
    int NT = (NW + 4095) / 4096;               // 263 tiles (<=512)
    int NWp = NT * 4096;

    float* km = (float*)d_out;                 // [NK,3]
    float* out_key = km + (size_t)NK * 3;      // [NK,3]
    float* outF = km + (size_t)NK * 6;         // [NK,32]

    char* w = (char*)d_ws;
    char* p_bits    = w; w += ((size_t)NWp * 8 + 15) & ~(size_t)15;
    char* p_multibk = w; w += ((size_t)nkw * 4 + 15) & ~(size_t)15;
    char* p_cnts    = w; w += 16;
    size_t zbytes   = (size_t)(w - (char*)d_ws);
    char* p_tsums   = w; w += ((size_t)(NT + 1) * 4 + 15) & ~(size_t)15;
    char* p_wpref   = w; w += ((size_t)NWp * 4 + 15) & ~(size_t)15;
    char* p_minE    = w; w += ((size_t)NK * 4 + 15) & ~(size_t)15;
    char* p_kid     = w; w += ((size_t)NKp * 4 + 15) & ~(size_t)15;
    char* p_rank    = w; w += ((size_t)NK * 4 + 15) & ~(size_t)15;
    char* p_bsums   = w; w += ((size_t)(NB + 1) * 4 + 15) & ~(size_t)15;

    u64* bits     = (u64*)p_bits;
    u32* multibk  = (u32*)p_multibk;
    u32* cnts     = (u32*)p_cnts;
    int* tsums    = (int*)p_tsums;
    u32* wprefix  = (u32*)p_wpref;
    int* minE     = (int*)p_minE;
    int* kid      = (int*)p_kid;
    int* rank_key = (int*)p_rank;
    int* bsums    = (int*)p_bsums;

    hipMemsetAsync(d_ws, 0, zbytes, stream);   // bits + multibk + counters

    int nb9 = (N * 9 + 255) / 256;
    k_mark<<<nb9, 256, 0, stream>>>(si, N, bits);
    s1_tilesum<<<NT, 512, 0, stream>>>(bits, tsums, minE, NK, NT, cnts);
    s3_wprefix<<<NT, 256, 0, stream>>>(bits, tsums, wprefix);
    k_kid<<<nb9, 256, 0, stream>>>(si, N, bits, wprefix, kid, minE);
    k_flagsum<<<NB, 1024, 0, stream>>>(kid, minE, NK, NB, multibk, bsums, cnts + 1);
    k_scanC<<<NB, 256, 0, stream>>>(kid, minE, bsums, si, multibk, N, NK, NB,
                                    out_key, rank_key, (float4*)outF);
    k_final<<<(NK * 8 + 255) / 256, 256, 0, stream>>>(kid, rank_key, multibk,
                                                      feat4, km, outF, NK);
}

// Round 9
// 698.940 us; speedup vs baseline: 1.3757x; 1.3757x over previous
//
#include <hip/hip_runtime.h>
#include <stdint.h>

typedef unsigned long long u64;
typedef unsigned u32;
typedef float __attribute__((ext_vector_type(4))) f4raw;

#define K 27
#define S 258
#define ENCMAX (4 * S * S * S)        // 68,694,048 possible keys

// ---------- pass 1: mark presence bits (one u64 atomicOr per z-run) ----------
__global__ void k_mark(const int* __restrict__ si, int N, u64* __restrict__ bits) {
    int idx = blockIdx.x * blockDim.x + threadIdx.x;
    if (idx >= N * 9) return;
    int n = idx / 9, run = idx - n * 9;
    int ox = run / 3, oy = run - ox * 3;
    int b = si[n], x = si[N + n], y = si[2 * N + n], z = si[3 * N + n];
    unsigned enc0 = (unsigned)(((b * S + x + ox) * S + (y + oy)) * S + z);
    unsigned w = enc0 >> 6; int bit = enc0 & 63;
    atomicOr(&bits[w], 7ull << bit);
    if (bit > 61) atomicOr(&bits[w + 1], 7ull >> (64 - bit));
}

// ---------- s1: per-4096-word tile popcount sums ----------
__global__ void s1_tilesum(const u64* __restrict__ bits, int* __restrict__ tsums) {
    __shared__ int s[256];
    int tid = threadIdx.x;
    const u64* p = bits + (size_t)blockIdx.x * 4096;
    int sum = 0;
    for (int j = tid; j < 4096; j += 256) sum += __popcll(p[j]);
    s[tid] = sum; __syncthreads();
    for (int off = 128; off > 0; off >>= 1) {
        if (tid < off) s[tid] += s[tid + off];
        __syncthreads();
    }
    if (tid == 0) tsums[blockIdx.x] = s[0];
}

// ---------- single-block exclusive scan (n <= 1024); total -> a[n] ----------
__global__ void k_scanB(int* __restrict__ a, int n) {
    __shared__ int s[1024];
    int tid = threadIdx.x;
    int v = (tid < n) ? a[tid] : 0;
    s[tid] = v; __syncthreads();
    for (int off = 1; off < 1024; off <<= 1) {
        int t = (tid >= off) ? s[tid - off] : 0;
        __syncthreads();
        s[tid] += t;
        __syncthreads();
    }
    if (tid == 1023) a[n] = s[1023];
    if (tid < n) a[tid] = s[tid] - v;
}

// ---------- s3: per-word exclusive popcount prefix ----------
__global__ void s3_wprefix(const u64* __restrict__ bits, const int* __restrict__ tsums,
                           u32* __restrict__ wprefix) {
    __shared__ int s[256];
    int tid = threadIdx.x;
    size_t base = (size_t)blockIdx.x * 4096 + (size_t)tid * 16;
    int pc[16]; int tsum = 0;
#pragma unroll
    for (int j = 0; j < 16; j++) { pc[j] = __popcll(bits[base + j]); tsum += pc[j]; }
    s[tid] = tsum; __syncthreads();
    for (int off = 1; off < 256; off <<= 1) {
        int t = (tid >= off) ? s[tid - off] : 0;
        __syncthreads();
        s[tid] += t;
        __syncthreads();
    }
    int run = tsums[blockIdx.x] + s[tid] - tsum;
#pragma unroll
    for (int j = 0; j < 16; j++) { wprefix[base + j] = (u32)run; run += pc[j]; }
}

// ---------- pass 2: dense key id per entry + min-e per key (L2-hot atomics) ---
__global__ void k_kid(const int* __restrict__ si, int N,
                      const u64* __restrict__ bits, const u32* __restrict__ wprefix,
                      int* __restrict__ kid, int* __restrict__ minE) {
    int idx = blockIdx.x * blockDim.x + threadIdx.x;
    if (idx >= N * 9) return;
    int n = idx / 9, run = idx - n * 9;
    int ox = run / 3, oy = run - ox * 3;
    int b = si[n], x = si[N + n], y = si[2 * N + n], z = si[3 * N + n];
    unsigned enc0 = (unsigned)(((b * S + x + ox) * S + (y + oy)) * S + z);
    int e0 = n * K + run * 3;
#pragma unroll
    for (int oz = 0; oz < 3; ++oz) {
        unsigned enc = enc0 + oz;
        unsigned w = enc >> 6; int bit = enc & 63;
        int kd = (int)wprefix[w] + __popcll(bits[w] & ((1ull << bit) - 1));
        kid[e0 + oz] = kd;
        atomicMin(&minE[kd], e0 + oz);
    }
}

// ---------- pass 3: flags via wave ballot -> bitmap; tile sums; multi bitmap --
__global__ void k_flagsum(const int* __restrict__ kid, const int* __restrict__ minE,
                          int NK, u32* __restrict__ multibk,
                          u64* __restrict__ flagw, int* __restrict__ bsums) {
    __shared__ int s[256];
    int tid = threadIdx.x;
    int tilebase = blockIdx.x * 4096;
    int sum = 0;
#pragma unroll
    for (int j = 0; j < 16; j++) {
        int e = tilebase + j * 256 + tid;
        int f = 0;
        if (e < NK) {
            int kd = kid[e];
            if (minE[kd] == e) f = 1;
            else atomicOr(&multibk[kd >> 5], 1u << (kd & 31));   // ~70k total
        }
        u64 b = __ballot(f);
        if ((tid & 63) == 0) flagw[(unsigned)e >> 6] = b;
        sum += f;
    }
    s[tid] = sum; __syncthreads();
    for (int off = 128; off > 0; off >>= 1) {
        if (tid < off) s[tid] += s[tid + off];
        __syncthreads();
    }
    if (tid == 0) bsums[blockIdx.x] = s[0];
}

// ---------- scan C: ranks, out_key, rank_key, multi-row zero, tail ----------
// flags come from the sequential 340KB flagw bitmap (no random minE gathers)
__global__ void k_scanC(const int* __restrict__ kid, const u64* __restrict__ flagw,
                        const int* __restrict__ bsums, const int* __restrict__ si,
                        const u32* __restrict__ multibk, int N, int NK, int NB,
                        float* __restrict__ out_key, int* __restrict__ rank_key,
                        float4* __restrict__ outF4) {
    __shared__ int s[256];
    int tid = threadIdx.x;
    int base = blockIdx.x * 4096 + tid * 16;
    int kv[16];
    *(int4*)(kv + 0)  = *(const int4*)(kid + base + 0);
    *(int4*)(kv + 4)  = *(const int4*)(kid + base + 4);
    *(int4*)(kv + 8)  = *(const int4*)(kid + base + 8);
    *(int4*)(kv + 12) = *(const int4*)(kid + base + 12);
    u64 word = flagw[(unsigned)base >> 6];            // 4 threads share a word
    int fbits = (int)((word >> ((tid & 3) * 16)) & 0xFFFFu);
    int tsum = __popc(fbits);
    s[tid] = tsum; __syncthreads();
    for (int off = 1; off < 256; off <<= 1) {
        int t = (tid >= off) ? s[tid - off] : 0;
        __syncthreads();
        s[tid] += t;
        __syncthreads();
    }
    int offset = bsums[blockIdx.x] + s[tid] - tsum;
    float4 zf = {0.f, 0.f, 0.f, 0.f};
    int run = 0;
#pragma unroll
    for (int j = 0; j < 16; j++) {
        int e = base + j;
        int f = (fbits >> j) & 1;
        if (f) {
            int rank = offset + run;
            int n = e / K; int m = e - n * K;
            int x = si[N + n], y = si[2 * N + n], z = si[3 * N + n];
            int ox = m / 9; int rm = m - ox * 9; int oy = rm / 3; int oz = rm - oy * 3;
            out_key[(size_t)rank * 3 + 0] = (float)(x + ox - 1);
            out_key[(size_t)rank * 3 + 1] = (float)(y + oy - 1);
            out_key[(size_t)rank * 3 + 2] = (float)(z + oz - 1);
            int kd = kv[j];
            rank_key[kd] = rank;
            if ((multibk[kd >> 5] >> (kd & 31)) & 1) {    // multi row: pre-zero
                float4* q = outF4 + (size_t)rank * 8;
#pragma unroll
                for (int q8 = 0; q8 < 8; q8++) q[q8] = zf;
            }
        }
        run += f;
    }
    // tail rows >= U: outF=0, out_key=-1
    int U = bsums[NB];
    int rows = NK - U;
    int gs = gridDim.x * blockDim.x;
    for (int i = blockIdx.x * blockDim.x + tid; i < rows; i += gs) {
        int row = U + i;
        float4* q = outF4 + (size_t)row * 8;
#pragma unroll
        for (int q8 = 0; q8 < 8; q8++) q[q8] = zf;
        out_key[(size_t)row * 3 + 0] = -1.0f;
        out_key[(size_t)row * 3 + 1] = -1.0f;
        out_key[(size_t)row * 3 + 2] = -1.0f;
    }
}

// ---------- final: kernel_map + coalesced feature scatter (8 lanes/row) ------
__global__ void k_final(const int* __restrict__ kid, const int* __restrict__ rank_key,
                        const u32* __restrict__ multibk,
                        const float4* __restrict__ feat4,
                        float* __restrict__ km, float* __restrict__ outF, int NK) {
    int idx = blockIdx.x * blockDim.x + threadIdx.x;
    if (idx >= NK * 8) return;
    int e = idx >> 3, g = idx & 7;
    int kd = kid[e];                              // 8 lanes same addr -> broadcast
    int uid = rank_key[kd];                       // one hot gather
    int multi = (multibk[kd >> 5] >> (kd & 31)) & 1;
    int n = e / K, m = e - n * K;
    float4 v = feat4[(size_t)n * 8 + g];
    float* dst = outF + (size_t)uid * 32 + g * 4;
    if (multi) {
        atomicAdd(dst + 0, v.x);
        atomicAdd(dst + 1, v.y);
        atomicAdd(dst + 2, v.z);
        atomicAdd(dst + 3, v.w);
    } else {
        f4raw vr = {v.x, v.y, v.z, v.w};
        __builtin_nontemporal_store(vr, (f4raw*)dst);   // 346MB write-once stream
    }
    if (g < 3)
        km[(size_t)e * 3 + g] = (g == 0) ? (float)n
                               : ((g == 1) ? (float)uid : (float)m);
}

extern "C" void kernel_launch(void* const* d_in, const int* in_sizes, int n_in,
                              void* d_out, int out_size, void* d_ws, size_t ws_size,
                              hipStream_t stream) {
    const int* si = (const int*)d_in[0];
    const float4* feat4 = (const float4*)d_in[1];
    int N = in_sizes[0] / 4;
    int NK = N * K;                            // 2,700,000
    int NKp = (NK + 4095) & ~4095;
    int NB = NKp / 4096;                       // ~660 (<=1024)
    int nkw = (NK + 31) / 32;

    int NW = (ENCMAX + 63) / 64;               // 1,073,345 bitmap words
    int NT = (NW + 4095) / 4096;               // 263 tiles (<=1024)
    int NWp = NT * 4096;

    float* km = (float*)d_out;                 // [NK,3]
    float* out_key = km + (size_t)NK * 3;      // [NK,3]
    float* outF = km + (size_t)NK * 6;         // [NK,32]

    char* w = (char*)d_ws;
    char* p_bits    = w; w += ((size_t)NWp * 8 + 15) & ~(size_t)15;
    char* p_multibk = w; w += ((size_t)nkw * 4 + 15) & ~(size_t)15;
    size_t zbytes   = (size_t)(w - (char*)d_ws);       // zeroed in one memset
    char* p_tsums   = w; w += ((size_t)(NT + 1) * 4 + 15) & ~(size_t)15;
    char* p_wpref   = w; w += ((size_t)NWp * 4 + 15) & ~(size_t)15;
    char* p_minE    = w; w += ((size_t)NK * 4 + 15) & ~(size_t)15;
    char* p_kid     = w; w += ((size_t)NKp * 4 + 15) & ~(size_t)15;
    char* p_rank    = w; w += ((size_t)NK * 4 + 15) & ~(size_t)15;
    char* p_flagw   = w; w += ((size_t)(NKp / 64) * 8 + 15) & ~(size_t)15;
    char* p_bsums   = w; w += ((size_t)(NB + 1) * 4 + 15) & ~(size_t)15;

    u64* bits     = (u64*)p_bits;
    u32* multibk  = (u32*)p_multibk;
    int* tsums    = (int*)p_tsums;
    u32* wprefix  = (u32*)p_wpref;
    int* minE     = (int*)p_minE;
    int* kid      = (int*)p_kid;
    int* rank_key = (int*)p_rank;
    u64* flagw    = (u64*)p_flagw;
    int* bsums    = (int*)p_bsums;

    (void)hipMemsetAsync(d_ws, 0, zbytes, stream);             // bits + multibk
    (void)hipMemsetAsync(minE, 0x7F, (size_t)NK * 4, stream);  // +INF for atomicMin

    int nb9 = (N * 9 + 255) / 256;
    k_mark<<<nb9, 256, 0, stream>>>(si, N, bits);
    s1_tilesum<<<NT, 256, 0, stream>>>(bits, tsums);
    k_scanB<<<1, 1024, 0, stream>>>(tsums, NT);
    s3_wprefix<<<NT, 256, 0, stream>>>(bits, tsums, wprefix);
    k_kid<<<nb9, 256, 0, stream>>>(si, N, bits, wprefix, kid, minE);
    k_flagsum<<<NB, 256, 0, stream>>>(kid, minE, NK, multibk, flagw, bsums);
    k_scanB<<<1, 1024, 0, stream>>>(bsums, NB);
    k_scanC<<<NB, 256, 0, stream>>>(kid, flagw, bsums, si, multibk, N, NK, NB,
                                    out_key, rank_key, (float4*)outF);
    k_final<<<(NK * 8 + 255) / 256, 256, 0, stream>>>(kid, rank_key, multibk,
                                                      feat4, km, outF, NK);
}